// Round 9
// baseline (1745.385 us; speedup 1.0000x reference)
//
#include <hip/hip_runtime.h>
#include <math.h>

#define D_   1024
#define H_   16
#define DK_  64
#define L_   512
#define NB_  16
#define FF_  4096
#define M_   (NB_*L_)   // 8192 tokens
#define EPS_ 1e-5f

typedef __attribute__((ext_vector_type(8))) __bf16 bf16x8;
typedef __attribute__((ext_vector_type(4))) float f32x4;
typedef __attribute__((ext_vector_type(4))) unsigned short us4;
typedef __attribute__((ext_vector_type(8))) unsigned short us8;
typedef __attribute__((ext_vector_type(4))) unsigned int u32x4;

__device__ __forceinline__ float gelu_exact(float x){
    return 0.5f * x * (1.f + erff(x * 0.7071067811865476f));
}

// split fp32 -> bf16 hi (truncate) + bf16 lo (truncated remainder), packed:
// low 16 bits = hi part, high 16 bits = lo part. ~2^-16 rel err on product.
__device__ __forceinline__ unsigned split1(float a){
    unsigned ab = __builtin_bit_cast(unsigned, a);
    unsigned short h = (unsigned short)(ab >> 16);
    float hif = __builtin_bit_cast(float, ab & 0xffff0000u);
    float rem = a - hif;
    unsigned short lo = (unsigned short)(__builtin_bit_cast(unsigned, rem) >> 16);
    return (unsigned)h | ((unsigned)lo << 16);
}

__device__ __forceinline__ void split4v(float4 x, us4& h, us4& lo){
    unsigned p0 = split1(x.x), p1 = split1(x.y), p2 = split1(x.z), p3 = split1(x.w);
    h.x = (unsigned short)p0; lo.x = (unsigned short)(p0 >> 16);
    h.y = (unsigned short)p1; lo.y = (unsigned short)(p1 >> 16);
    h.z = (unsigned short)p2; lo.z = (unsigned short)(p2 >> 16);
    h.w = (unsigned short)p3; lo.w = (unsigned short)(p3 >> 16);
}

__device__ __forceinline__ void split8v(float4 x, float4 y, bf16x8& h, bf16x8& lo){
    us8 hu, lu; unsigned p;
    p = split1(x.x); hu[0]=(unsigned short)p; lu[0]=(unsigned short)(p>>16);
    p = split1(x.y); hu[1]=(unsigned short)p; lu[1]=(unsigned short)(p>>16);
    p = split1(x.z); hu[2]=(unsigned short)p; lu[2]=(unsigned short)(p>>16);
    p = split1(x.w); hu[3]=(unsigned short)p; lu[3]=(unsigned short)(p>>16);
    p = split1(y.x); hu[4]=(unsigned short)p; lu[4]=(unsigned short)(p>>16);
    p = split1(y.y); hu[5]=(unsigned short)p; lu[5]=(unsigned short)(p>>16);
    p = split1(y.z); hu[6]=(unsigned short)p; lu[6]=(unsigned short)(p>>16);
    p = split1(y.w); hu[7]=(unsigned short)p; lu[7]=(unsigned short)(p>>16);
    h = __builtin_bit_cast(bf16x8, hu);
    lo = __builtin_bit_cast(bf16x8, lu);
}

// async global -> LDS, 16 bytes per lane (linear dest: lds base + lane*16)
__device__ __forceinline__ void gl16(const unsigned short* g, unsigned short* l){
    __builtin_amdgcn_global_load_lds(
        (const __attribute__((address_space(1))) unsigned int*)g,
        (__attribute__((address_space(3))) unsigned int*)l, 16, 0, 0);
}

// ---------------------------------------------------------------------------
// Weight pre-split: W[K,N] fp32 -> fragment-lane-order bf16 hi/lo tiles.
// Tile (nb, ks) = 128 cols x 32 k: [hi 4096 shorts][lo 4096 shorts], tile
// stride 8192 shorts. Element (k,c): s=c>>4, l=(k>>3)*16+(c&15), j=k&7,
// off = s*512 + l*8 + j. Grid: (K/32, N/128), 256 thr.
// ---------------------------------------------------------------------------
__global__ __launch_bounds__(256)
void wsplit_k(const float* __restrict__ W, unsigned short* __restrict__ out,
              int K, int N)
{
    const int ks = blockIdx.x, nb = blockIdx.y;
    unsigned short* tb = out + ((size_t)nb * (K >> 5) + ks) * 8192;
    const int t = threadIdx.x;
#pragma unroll
    for (int it = 0; it < 2; ++it) {
        const int slot = t + it * 256;        // 0..511
        const int c = slot & 127, ko = slot >> 7;
        us8 h, lo;
#pragma unroll
        for (int j = 0; j < 8; ++j) {
            float wv = W[(size_t)(ks * 32 + ko * 8 + j) * N + nb * 128 + c];
            unsigned p = split1(wv);
            h[j] = (unsigned short)p; lo[j] = (unsigned short)(p >> 16);
        }
        const int off = ((c >> 4) * 512) + (ko * 16 + (c & 15)) * 8;
        *(us8*)&tb[off] = h;
        *(us8*)&tb[4096 + off] = lo;
    }
}

// ---------------------------------------------------------------------------
// Split-bf16 MFMA GEMM, B pre-split (frag-layout) + global_load_lds staging.
// C = A[M,K] @ B[K,N] + bias, fused epilogue.
// EPI 0: scatter [n,h,l,dk]  EPI 1: +res  EPI 2: GELU  EPI 3: scatter V^T
// A LDS subtile stride padded 512->520 shorts (kills 4-way write conflicts).
// ---------------------------------------------------------------------------
template<int EPI>
__global__ __launch_bounds__(256, 4)
void gemm_mfma(const float* __restrict__ A, const unsigned short* __restrict__ Bw,
               const float* __restrict__ bias, const float* __restrict__ res,
               float* __restrict__ C, int M, int N, int K)
{
    __shared__ __align__(16) unsigned short Ah[4160];   // 8 subtiles x 520
    __shared__ __align__(16) unsigned short Al[4160];
    __shared__ __align__(16) unsigned short Bs[8192];   // [hi 4096][lo 4096]

    const int t = threadIdx.x;
    const int nb = blockIdx.x;
    const int bm = blockIdx.y * 128, bn = nb * 128;
    const int l = t & 63, w = t >> 6, wr = w >> 1, wc = w & 1;
    const int nk = K >> 5;

    size_t gA[4]; int lA[4];
#pragma unroll
    for (int i = 0; i < 4; ++i) {
        int f = t + 256 * i;
        int r = f >> 3, k0 = (f & 7) * 4;
        gA[i] = (size_t)(bm + r) * K + k0;
        lA[i] = (r >> 4) * 520 + (((k0 >> 3) << 4) + (r & 15)) * 8 + (k0 & 7);
    }
    const unsigned short* wtile = Bw + (size_t)nb * nk * 8192;

    f32x4 acc[4][4] = {};

    float4 aA[4];
#pragma unroll
    for (int i = 0; i < 4; ++i) aA[i] = *(const float4*)&A[gA[i]];

    for (int ks = 0; ks < nk; ++ks) {
        __syncthreads();                       // prev-iter LDS reads done
        // ---- B: async DMA of pre-split tile (hi 8KB + lo 8KB) ----
        const unsigned short* tb = wtile + (size_t)ks * 8192;
        gl16(tb + t * 8,        Bs + t * 8);
        gl16(tb + 2048 + t * 8, Bs + 2048 + t * 8);
        gl16(tb + 4096 + t * 8, Bs + 4096 + t * 8);
        gl16(tb + 6144 + t * 8, Bs + 6144 + t * 8);
        // ---- A: split + LDS write ----
#pragma unroll
        for (int i = 0; i < 4; ++i) {
            us4 h, lo;
            split4v(aA[i], h, lo);
            *(us4*)&Ah[lA[i]] = h;
            *(us4*)&Al[lA[i]] = lo;
        }
        __syncthreads();                       // drains vmcnt+lgkm: tile ready
        if (ks + 1 < nk) {                     // prefetch next A while computing
            const int ko = (ks + 1) * 32;
#pragma unroll
            for (int i = 0; i < 4; ++i) aA[i] = *(const float4*)&A[gA[i] + ko];
        }
        bf16x8 ah[4], al4[4];
#pragma unroll
        for (int m = 0; m < 4; ++m) {
            const int idx = (wr * 4 + m) * 520 + l * 8;
            ah[m]  = *(const bf16x8*)&Ah[idx];
            al4[m] = *(const bf16x8*)&Al[idx];
        }
#pragma unroll
        for (int n = 0; n < 4; ++n) {
            const int idx = (wc * 4 + n) * 512 + l * 8;
            bf16x8 bh = *(const bf16x8*)&Bs[idx];
            bf16x8 bl = *(const bf16x8*)&Bs[4096 + idx];
#pragma unroll
            for (int m = 0; m < 4; ++m) {
                acc[m][n] = __builtin_amdgcn_mfma_f32_16x16x32_bf16(ah[m],  bh, acc[m][n], 0, 0, 0);
                acc[m][n] = __builtin_amdgcn_mfma_f32_16x16x32_bf16(ah[m],  bl, acc[m][n], 0, 0, 0);
                acc[m][n] = __builtin_amdgcn_mfma_f32_16x16x32_bf16(al4[m], bh, acc[m][n], 0, 0, 0);
            }
        }
    }

#pragma unroll
    for (int n = 0; n < 4; ++n) {
        const int col = bn + wc * 64 + n * 16 + (l & 15);
        const float bv = bias[col];
#pragma unroll
        for (int m = 0; m < 4; ++m) {
            const int rowb = bm + wr * 64 + m * 16 + ((l >> 4) << 2);
#pragma unroll
            for (int j = 0; j < 4; ++j) {
                const int row = rowb + j;
                float v = acc[m][n][j] + bv;
                if (EPI == 0) {
                    const int nbx = row >> 9, ll = row & (L_ - 1);
                    const int hh = col >> 6, d = col & (DK_ - 1);
                    C[(((size_t)nbx * H_ + hh) * L_ + ll) * DK_ + d] = v;
                } else if (EPI == 1) {
                    v += res[(size_t)row * N + col];
                    C[(size_t)row * N + col] = v;
                } else if (EPI == 2) {
                    C[(size_t)row * N + col] = gelu_exact(v);
                } else {                         // EPI 3: V^T scatter [n,h,dk,l]
                    const int nbx = row >> 9, ll = row & (L_ - 1);
                    const int hh = col >> 6, d = col & (DK_ - 1);
                    C[(((size_t)nbx * H_ + hh) * DK_ + d) * L_ + ll] = v;
                }
            }
        }
    }
}

// ---------------------------------------------------------------------------
// MFMA flash-ish attention, split-bf16 precision (unchanged from round 6).
// ---------------------------------------------------------------------------
__global__ __launch_bounds__(512, 1)
void attn_mfma(const float* __restrict__ qb, const float* __restrict__ kb,
               const float* __restrict__ vt, const unsigned char* __restrict__ mask,
               float* __restrict__ ctx)
{
    __shared__ unsigned Sp[64 * 512];                   // 128 KiB
    __shared__ __align__(16) unsigned short KVh[4096];  // 8 KiB
    __shared__ __align__(16) unsigned short KVl[4096];  // 8 KiB

    const int t = threadIdx.x;
    const int l = t & 63, w = t >> 6;
    const int qsub = w & 3;
    const int ksub = w >> 2;
    const int qt = blockIdx.x;
    const int nh = blockIdx.y;
    const int n = nh >> 4, hh = nh & 15;
    const int q0 = qt * 64;

    const float* qbase = qb + (size_t)nh * L_ * DK_;
    const float* kbase = kb + (size_t)nh * L_ * DK_;
    const float* vbase = vt + (size_t)nh * DK_ * L_;

    bf16x8 qh[2], ql[2];
#pragma unroll
    for (int ks = 0; ks < 2; ++ks) {
        const size_t qa = (size_t)(q0 + qsub * 16 + (l & 15)) * DK_ + ks * 32 + (l >> 4) * 8;
        float4 a0 = *(const float4*)&qbase[qa];
        float4 a1 = *(const float4*)&qbase[qa + 4];
        split8v(a0, a1, qh[ks], ql[ks]);
    }

    float4 pf[2];
#pragma unroll
    for (int i = 0; i < 2; ++i) {
        int f = t + 512 * i, r = f >> 4, k0 = (f & 15) * 4;
        pf[i] = *(const float4*)&kbase[(size_t)r * DK_ + k0];
    }
    for (int kt = 0; kt < 8; ++kt) {
        __syncthreads();
#pragma unroll
        for (int i = 0; i < 2; ++i) {
            int f = t + 512 * i, r = f >> 4, k0 = (f & 15) * 4;
            int off = (((r >> 4) * 2 + (k0 >> 5)) << 9) + ((((k0 & 31) >> 3) << 4) + (r & 15)) * 8 + (k0 & 7);
            us4 h, lo; split4v(pf[i], h, lo);
            *(us4*)&KVh[off] = h; *(us4*)&KVl[off] = lo;
        }
        __syncthreads();
        if (kt < 7) {
#pragma unroll
            for (int i = 0; i < 2; ++i) {
                int f = t + 512 * i, r = f >> 4, k0 = (f & 15) * 4;
                pf[i] = *(const float4*)&kbase[(size_t)((kt + 1) * 64 + r) * DK_ + k0];
            }
        }
        f32x4 acc2[2] = {};
#pragma unroll
        for (int ks = 0; ks < 2; ++ks) {
#pragma unroll
            for (int b = 0; b < 2; ++b) {
                const int off = (((ksub * 2 + b) * 2 + ks) << 9) + l * 8;
                bf16x8 bh = *(const bf16x8*)&KVh[off];
                bf16x8 bl = *(const bf16x8*)&KVl[off];
                acc2[b] = __builtin_amdgcn_mfma_f32_16x16x32_bf16(qh[ks], bh, acc2[b], 0, 0, 0);
                acc2[b] = __builtin_amdgcn_mfma_f32_16x16x32_bf16(qh[ks], bl, acc2[b], 0, 0, 0);
                acc2[b] = __builtin_amdgcn_mfma_f32_16x16x32_bf16(ql[ks], bh, acc2[b], 0, 0, 0);
            }
        }
#pragma unroll
        for (int b = 0; b < 2; ++b) {
            const int col = kt * 64 + (ksub * 2 + b) * 16 + (l & 15);
#pragma unroll
            for (int j = 0; j < 4; ++j) {
                const int row = qsub * 16 + (l >> 4) * 4 + j;
                const int word = row * 512 + ((((col >> 2) ^ (row & 7)) << 2) | (col & 3));
                Sp[word] = split1(acc2[b][j] * 0.125f);
            }
        }
    }
    __syncthreads();

    {
        const int row = t >> 3, seg = t & 7;
        const unsigned* mrow = (const unsigned*)(mask + ((size_t)n * L_ + q0 + row) * L_ + seg * 64);
        unsigned mb[16];
#pragma unroll
        for (int j2 = 0; j2 < 16; ++j2) mb[j2] = mrow[j2];
        float sum = 0.f;
#pragma unroll
        for (int i = 0; i < 64; ++i) {
            const int col = seg * 64 + i;
            const int word = row * 512 + ((((col >> 2) ^ (row & 7)) << 2) | (i & 3));
            unsigned u = Sp[word];
            float val = __builtin_bit_cast(float, (u & 0xffffu) << 16)
                      + __builtin_bit_cast(float, u & 0xffff0000u);
            if (!((mb[i >> 2] >> ((i & 3) * 8)) & 0xffu)) sum += __expf(val);
        }
        sum += __shfl_xor(sum, 1); sum += __shfl_xor(sum, 2); sum += __shfl_xor(sum, 4);
        const float inv = sum > 0.f ? 1.f / sum : 0.f;
#pragma unroll
        for (int i = 0; i < 64; ++i) {
            const int col = seg * 64 + i;
            const int word = row * 512 + ((((col >> 2) ^ (row & 7)) << 2) | (i & 3));
            unsigned u = Sp[word];
            float val = __builtin_bit_cast(float, (u & 0xffffu) << 16)
                      + __builtin_bit_cast(float, u & 0xffff0000u);
            float p = ((mb[i >> 2] >> ((i & 3) * 8)) & 0xffu) ? 0.f : __expf(val) * inv;
            Sp[word] = split1(p);
        }
    }

    f32x4 oacc[2] = {};
#pragma unroll
    for (int i = 0; i < 2; ++i) {
        int f = t + 512 * i, d = f >> 4, key0 = (f & 15) * 4;
        pf[i] = *(const float4*)&vbase[(size_t)d * L_ + key0];
    }
    for (int kt = 0; kt < 8; ++kt) {
        __syncthreads();
#pragma unroll
        for (int i = 0; i < 2; ++i) {
            int f = t + 512 * i, d = f >> 4, key0 = (f & 15) * 4;
            int off = (((d >> 4) * 2 + (key0 >> 5)) << 9) + ((((key0 & 31) >> 3) << 4) + (d & 15)) * 8 + (key0 & 7);
            us4 h, lo; split4v(pf[i], h, lo);
            *(us4*)&KVh[off] = h; *(us4*)&KVl[off] = lo;
        }
        __syncthreads();
        if (kt < 7) {
#pragma unroll
            for (int i = 0; i < 2; ++i) {
                int f = t + 512 * i, d = f >> 4, key0 = (f & 15) * 4;
                pf[i] = *(const float4*)&vbase[(size_t)d * L_ + (kt + 1) * 64 + key0];
            }
        }
#pragma unroll
        for (int ks = 0; ks < 2; ++ks) {
            const int rowpv = qsub * 16 + (l & 15);
            const int sw = rowpv & 7;
            const int g0 = kt * 16 + ks * 8 + (l >> 4) * 2;
            u32x4 Ua = *(const u32x4*)&Sp[rowpv * 512 + ((g0 ^ sw) << 2)];
            u32x4 Ub = *(const u32x4*)&Sp[rowpv * 512 + (((g0 + 1) ^ sw) << 2)];
            us8 hu, lu;
            hu[0]=(unsigned short)Ua[0]; lu[0]=(unsigned short)(Ua[0]>>16);
            hu[1]=(unsigned short)Ua[1]; lu[1]=(unsigned short)(Ua[1]>>16);
            hu[2]=(unsigned short)Ua[2]; lu[2]=(unsigned short)(Ua[2]>>16);
            hu[3]=(unsigned short)Ua[3]; lu[3]=(unsigned short)(Ua[3]>>16);
            hu[4]=(unsigned short)Ub[0]; lu[4]=(unsigned short)(Ub[0]>>16);
            hu[5]=(unsigned short)Ub[1]; lu[5]=(unsigned short)(Ub[1]>>16);
            hu[6]=(unsigned short)Ub[2]; lu[6]=(unsigned short)(Ub[2]>>16);
            hu[7]=(unsigned short)Ub[3]; lu[7]=(unsigned short)(Ub[3]>>16);
            bf16x8 ph = __builtin_bit_cast(bf16x8, hu);
            bf16x8 pl = __builtin_bit_cast(bf16x8, lu);
#pragma unroll
            for (int b = 0; b < 2; ++b) {
                const int off = (((ksub * 2 + b) * 2 + ks) << 9) + l * 8;
                bf16x8 vh = *(const bf16x8*)&KVh[off];
                bf16x8 vl = *(const bf16x8*)&KVl[off];
                oacc[b] = __builtin_amdgcn_mfma_f32_16x16x32_bf16(ph, vh, oacc[b], 0, 0, 0);
                oacc[b] = __builtin_amdgcn_mfma_f32_16x16x32_bf16(ph, vl, oacc[b], 0, 0, 0);
                oacc[b] = __builtin_amdgcn_mfma_f32_16x16x32_bf16(pl, vh, oacc[b], 0, 0, 0);
            }
        }
    }
#pragma unroll
    for (int b = 0; b < 2; ++b) {
        const int col = ksub * 32 + b * 16 + (l & 15);
#pragma unroll
        for (int j = 0; j < 4; ++j) {
            const int rowl = q0 + qsub * 16 + (l >> 4) * 4 + j;
            ctx[((size_t)n * L_ + rowl) * D_ + hh * 64 + col] = oacc[b][j];
        }
    }
}

// ---------------------------------------------------------------------------
// Row LayerNorm
// ---------------------------------------------------------------------------
__global__ __launch_bounds__(256)
void ln_k(const float* __restrict__ in, const float* __restrict__ g,
          const float* __restrict__ b, float* __restrict__ out)
{
    const int row = blockIdx.x, tid = threadIdx.x;
    const float* p = in + (size_t)row * D_;
    float4 v = *(const float4*)&p[tid * 4];
    float s = v.x + v.y + v.z + v.w;
#pragma unroll
    for (int off = 32; off > 0; off >>= 1) s += __shfl_down(s, off);
    __shared__ float wsum[4];
    const int wid = tid >> 6, lane = tid & 63;
    if (lane == 0) wsum[wid] = s;
    __syncthreads();
    const float mu = (wsum[0] + wsum[1] + wsum[2] + wsum[3]) * (1.f / D_);
    const float dx = v.x - mu, dy = v.y - mu, dz = v.z - mu, dw = v.w - mu;
    float q = dx * dx + dy * dy + dz * dz + dw * dw;
#pragma unroll
    for (int off = 32; off > 0; off >>= 1) q += __shfl_down(q, off);
    __syncthreads();
    if (lane == 0) wsum[wid] = q;
    __syncthreads();
    const float var = (wsum[0] + wsum[1] + wsum[2] + wsum[3]) * (1.f / D_);
    const float rs = rsqrtf(var + EPS_);
    const float4 gg = *(const float4*)&g[tid * 4];
    const float4 bb = *(const float4*)&b[tid * 4];
    float4 o;
    o.x = dx * rs * gg.x + bb.x;
    o.y = dy * rs * gg.y + bb.y;
    o.z = dz * rs * gg.z + bb.z;
    o.w = dw * rs * gg.w + bb.w;
    *(float4*)&out[(size_t)row * D_ + tid * 4] = o;
}

// ---------------------------------------------------------------------------
extern "C" void kernel_launch(void* const* d_in, const int* in_sizes, int n_in,
                              void* d_out, int out_size, void* d_ws, size_t ws_size,
                              hipStream_t stream)
{
    const float* x  = (const float*)d_in[0];
    const unsigned char* mask = (const unsigned char*)d_in[1];
    const float* WQ = (const float*)d_in[2];
    const float* bQ = (const float*)d_in[3];
    const float* WK = (const float*)d_in[4];
    const float* bK = (const float*)d_in[5];
    const float* WV = (const float*)d_in[6];
    const float* bV = (const float*)d_in[7];
    const float* WO = (const float*)d_in[8];
    const float* bO = (const float*)d_in[9];
    const float* g0 = (const float*)d_in[10];
    const float* b0 = (const float*)d_in[11];
    const float* W1 = (const float*)d_in[12];
    const float* b1 = (const float*)d_in[13];
    const float* W2 = (const float*)d_in[14];
    const float* b2 = (const float*)d_in[15];
    const float* g1 = (const float*)d_in[16];
    const float* b1n = (const float*)d_in[17];
    float* out = (float*)d_out;

    const size_t MD = (size_t)M_ * D_;
    float* ws   = (float*)d_ws;
    float* qbuf = ws;            // [n,h,l,dk]
    float* kbuf = ws + MD;       // [n,h,l,dk]; later ff2 output
    float* vbuf = ws + 2 * MD;   // V^T [n,h,dk,l]; after attn: W1s/W2s
    float* cbuf = ws + 3 * MD;   // ctx [n,l,d]
    float* fbuf = ws + 4 * MD;   // QKVO weight splits, then ff1 activations
    float* hbuf = out;           // h parked in d_out until final LN

    // split-weight buffers (each element -> 2 shorts; DxD weight = 4MB)
    unsigned short* WQs = (unsigned short*)fbuf;                   // 4MB
    unsigned short* WKs = WQs + 2ull * D_ * D_;                    // 4MB
    unsigned short* WVs = WQs + 4ull * D_ * D_;                    // 4MB
    unsigned short* WOs = WQs + 6ull * D_ * D_;                    // 4MB (<= 128MB region)
    unsigned short* W1s = (unsigned short*)vbuf;                   // 16MB
    unsigned short* W2s = (unsigned short*)vbuf + 2ull * D_ * FF_; // 16MB (vbuf = 32MB)

    dim3 blk(256);
    dim3 gD(D_ / 128, M_ / 128);    // (8, 64)
    dim3 gF(FF_ / 128, M_ / 128);   // (32, 64)

    // --- pre-split QKVO weights (live in fbuf region until FF1 overwrites) ---
    wsplit_k<<<dim3(D_ / 32, D_ / 128), blk, 0, stream>>>(WQ, WQs, D_, D_);
    wsplit_k<<<dim3(D_ / 32, D_ / 128), blk, 0, stream>>>(WK, WKs, D_, D_);
    wsplit_k<<<dim3(D_ / 32, D_ / 128), blk, 0, stream>>>(WV, WVs, D_, D_);
    wsplit_k<<<dim3(D_ / 32, D_ / 128), blk, 0, stream>>>(WO, WOs, D_, D_);

    gemm_mfma<0><<<gD, blk, 0, stream>>>(x, WQs, bQ, nullptr, qbuf, M_, D_, D_);
    gemm_mfma<0><<<gD, blk, 0, stream>>>(x, WKs, bK, nullptr, kbuf, M_, D_, D_);
    gemm_mfma<3><<<gD, blk, 0, stream>>>(x, WVs, bV, nullptr, vbuf, M_, D_, D_);   // V^T
    attn_mfma<<<dim3(L_ / 64, NB_ * H_), dim3(512), 0, stream>>>(qbuf, kbuf, vbuf, mask, cbuf);
    gemm_mfma<1><<<gD, blk, 0, stream>>>(cbuf, WOs, bO, x, qbuf, M_, D_, D_);      // mha + x
    ln_k<<<dim3(M_), blk, 0, stream>>>(qbuf, g0, b0, hbuf);                         // h

    // --- vbuf free now: pre-split FF weights into it ---
    wsplit_k<<<dim3(D_ / 32, FF_ / 128), blk, 0, stream>>>(W1, W1s, D_, FF_);
    wsplit_k<<<dim3(FF_ / 32, D_ / 128), blk, 0, stream>>>(W2, W2s, FF_, D_);

    gemm_mfma<2><<<gF, blk, 0, stream>>>(hbuf, W1s, b1, nullptr, fbuf, M_, FF_, D_);
    gemm_mfma<1><<<gD, blk, 0, stream>>>(fbuf, W2s, b2, hbuf, kbuf, M_, D_, FF_);  // ff + h
    ln_k<<<dim3(M_), blk, 0, stream>>>(kbuf, g1, b1n, out);
}